// Round 5
// baseline (116.399 us; speedup 1.0000x reference)
//
#include <hip/hip_runtime.h>

// Elman RNN, B=262144, IN=32, H=16, T=30, OUT=1, fp32 in/out.
// Round 10: TWO independent recurrence chains per wave (ILP-2).
// Post-mortem r8/9: pk-f32 issue cut was NEUTRAL -> loop is NOT issue-bound
// (issue slots only ~35% subscribed: 480 wave-steps x ~70cy = 34k cy vs 96k
// observed). The t-chain is serial (MFMA ~20cy -> exp2 -> mul/rcp chain ->
// pkrtz -> hazard nops ~ 80-120cy latency/step) => LATENCY-bound.
// The old "2x chains: neutral" null was measured in the pre-r7
// issue-congested regime; regime changed, so re-try:
//  - each wave owns 32 batch rows = two independent 16-row chains A/B;
//    compiler interleaves them, B's ops fill A's dependency stalls.
//  - 8192 waves = exactly 8/SIMD (one generation, no tail).
//  - W fragments (whh, afc, wh*/wl*, bias) shared; only xpv/s/acc/fc state
//    duplicated: ~52 VGPR, under the 64 cap for 8 waves/SIMD.
//  - per-chain numerics BIT-IDENTICAL to r9 (absmax must stay 0.015625).
// Loop body per chain (r8, verified): 1 fp16 MFMA recurrence + packed-dual
// fp32 tanh (4 exp2 + ONE shared rcp product-trick) + cvt_pkrtz repack +
// pipelined fc MFMA.
// Layout invariant (verified rounds 2-4): for 16x16x16 MFMA the B-fragment
// layout == C/D layout, so tanh(acc) repacks elementwise into the next B
// operand — the state stays transposed (S = H^T), never crosses lanes.

#define T_STEPS 30
#define BLOCK   128
#define SCALE   2.8853900817779268f   // 2*log2(e)

typedef _Float16 v4h __attribute__((ext_vector_type(4)));
typedef __fp16   v2fp __attribute__((ext_vector_type(2)));
typedef float    v4f __attribute__((ext_vector_type(4)));
typedef float    v2f __attribute__((ext_vector_type(2)));

struct h4 { v2fp lo, hi; };

static __device__ __forceinline__ v4h pack4(float a, float b, float c, float d) {
    h4 p;
    p.lo = __builtin_amdgcn_cvt_pkrtz(a, b);
    p.hi = __builtin_amdgcn_cvt_pkrtz(c, d);
    return __builtin_bit_cast(v4h, p);
}

__global__ __launch_bounds__(BLOCK, 8) void rnn_mfma(
    const float* __restrict__ x,     // [B, 32]
    const float* __restrict__ W_ih,  // [16, 32]
    const float* __restrict__ W_hh,  // [16, 16]
    const float* __restrict__ b_ih,  // [16]
    const float* __restrict__ b_hh,  // [16]
    const float* __restrict__ W_fc,  // [1, 16]
    const float* __restrict__ b_fc,  // [1]
    float* __restrict__ out)         // [B, 30]
{
    __shared__ float tmp[64 * T_STEPS];   // 64 rows/block x 30 steps

    const int tid  = threadIdx.x;
    const int w    = tid >> 6;        // wave in block (0..1), 32 rows each
    const int lane = tid & 63;
    const int r    = lane & 15;       // MFMA row index (batch row / A-row)
    const int q    = lane >> 4;       // quad
    const int j0   = 4 * q;

    const size_t rowA = (size_t)blockIdx.x * 64 + (size_t)w * 32 + r;
    const size_t rowB = rowA + 16;

    // ---- shared weight fragments --------------------------------------
    // A-frag (m=lane&15, k=4q+e): lane holds SCALE*W_ih[r][kh*16 + 4q+e].
    v4h wh0, wh1, wl0, wl1;
    v4f cbias;
    {
        float4 w0 = *(const float4*)(W_ih + r * 32 + 4 * q);
        float4 w1 = *(const float4*)(W_ih + r * 32 + 16 + 4 * q);
        w0.x *= SCALE; w0.y *= SCALE; w0.z *= SCALE; w0.w *= SCALE;
        w1.x *= SCALE; w1.y *= SCALE; w1.z *= SCALE; w1.w *= SCALE;
        wh0 = pack4(w0.x, w0.y, w0.z, w0.w);
        wh1 = pack4(w1.x, w1.y, w1.z, w1.w);
        wl0 = pack4(w0.x - (float)wh0[0], w0.y - (float)wh0[1],
                    w0.z - (float)wh0[2], w0.w - (float)wh0[3]);
        wl1 = pack4(w1.x - (float)wh1[0], w1.y - (float)wh1[1],
                    w1.z - (float)wh1[2], w1.w - (float)wh1[3]);
        const float4 bi = *(const float4*)(b_ih + j0);
        const float4 bh = *(const float4*)(b_hh + j0);
        cbias = (v4f){SCALE * (bi.x + bh.x), SCALE * (bi.y + bh.y),
                      SCALE * (bi.z + bh.z), SCALE * (bi.w + bh.w)};
    }

    // ---- xproj via split-precision MFMA chain, per chain ---------------
    // B-frag (k=4q+e, n=lane&15): lane holds x[row][kh*16 + 4q+e].
    v4f xpvA, xpvB;
#pragma unroll
    for (int cc = 0; cc < 2; ++cc) {
        const size_t row = cc ? rowB : rowA;
        const float4 x0 = *(const float4*)(x + row * 32 + 4 * q);
        const float4 x1 = *(const float4*)(x + row * 32 + 16 + 4 * q);
        v4h xh0 = pack4(x0.x, x0.y, x0.z, x0.w);
        v4h xh1 = pack4(x1.x, x1.y, x1.z, x1.w);
        v4h xl0 = pack4(x0.x - (float)xh0[0], x0.y - (float)xh0[1],
                        x0.z - (float)xh0[2], x0.w - (float)xh0[3]);
        v4h xl1 = pack4(x1.x - (float)xh1[0], x1.y - (float)xh1[1],
                        x1.z - (float)xh1[2], x1.w - (float)xh1[3]);
        v4f xp;
        xp = __builtin_amdgcn_mfma_f32_16x16x16f16(wh0, xh0, cbias, 0, 0, 0);
        xp = __builtin_amdgcn_mfma_f32_16x16x16f16(wh1, xh1, xp,    0, 0, 0);
        xp = __builtin_amdgcn_mfma_f32_16x16x16f16(wh0, xl0, xp,    0, 0, 0);
        xp = __builtin_amdgcn_mfma_f32_16x16x16f16(wh1, xl1, xp,    0, 0, 0);
        xp = __builtin_amdgcn_mfma_f32_16x16x16f16(wl0, xh0, xp,    0, 0, 0);
        xp = __builtin_amdgcn_mfma_f32_16x16x16f16(wl1, xh1, xp,    0, 0, 0);
        if (cc) xpvB = xp; else xpvA = xp;
    }

    // ---- W_hh A-fragment in fp16 (RNE): A[m=r][k=4q+i] = SCALE*W_hh[r][4q+i]
    v4h whh;
    {
        float4 wr = *(const float4*)(W_hh + r * 16 + 4 * q);
        whh[0] = (_Float16)(wr.x * SCALE);
        whh[1] = (_Float16)(wr.y * SCALE);
        whh[2] = (_Float16)(wr.z * SCALE);
        whh[3] = (_Float16)(wr.w * SCALE);
    }

    // ---- fc A-fragment (UNSCALED): row0 = fp16(W_fc), row1 = fp16 residual
    v4h afc;
#pragma unroll
    for (int i = 0; i < 4; ++i) {
        float wv = W_fc[4 * q + i];
        _Float16 hi = (_Float16)wv;
        _Float16 lo = (_Float16)(wv - (float)hi);
        afc[i] = (r == 0) ? hi : ((r == 1) ? lo : (_Float16)0.0f);
    }
    const float bfc = b_fc[0];
    const v4f zfc = {(q == 0) ? bfc : 0.0f, 0.0f, 0.0f, 0.0f};

    // ---- state S = H^T in fp16 (B-frag == C/D-frag layout)
    v4h sA = {(_Float16)0.0f, (_Float16)0.0f, (_Float16)0.0f, (_Float16)0.0f};
    v4h sB = sA;

    float* myoutA = &tmp[(w * 32 + r) * T_STEPS];        // lanes 0..15 write
    float* myoutB = &tmp[(w * 32 + 16 + r) * T_STEPS];

    const v2f one2  = {1.0f, 1.0f};
    const v2f mtwo2 = {-2.0f, -2.0f};

    v4f feA, foA, feB, foB;   // pipelined fc results (even / odd step)

#pragma unroll
    for (int t = 0; t < T_STEPS; ++t) {
        // Two independent chains; compiler interleaves so B fills A's stalls.
        v4f accA = __builtin_amdgcn_mfma_f32_16x16x16f16(whh, sA, xpvA, 0, 0, 0);
        v4f accB = __builtin_amdgcn_mfma_f32_16x16x16f16(whh, sB, xpvB, 0, 0, 0);

        // tanh = 1 - 2/(1+e), e = exp2(preact_scaled); packed dual-fp32
        // algebra (pairing U={0,2}, V={1,3}), ONE shared rcp per chain.
        v2f eUA = {__builtin_amdgcn_exp2f(accA[0]), __builtin_amdgcn_exp2f(accA[2])};
        v2f eVA = {__builtin_amdgcn_exp2f(accA[1]), __builtin_amdgcn_exp2f(accA[3])};
        v2f eUB = {__builtin_amdgcn_exp2f(accB[0]), __builtin_amdgcn_exp2f(accB[2])};
        v2f eVB = {__builtin_amdgcn_exp2f(accB[1]), __builtin_amdgcn_exp2f(accB[3])};

        v2f dUA = eUA + one2, dVA = eVA + one2;
        v2f dUB = eUB + one2, dVB = eVB + one2;
        v2f MA = dUA * dVA;                 // {m01, m23}
        v2f MB = dUB * dVB;
        float rrA = __builtin_amdgcn_rcpf(MA.x * MA.y);
        float rrB = __builtin_amdgcn_rcpf(MB.x * MB.y);
        v2f WswA = {rrA * MA.y, rrA * MA.x};
        v2f WswB = {rrB * MB.y, rrB * MB.x};
        v2f invUA = WswA * dVA, invVA = WswA * dUA;
        v2f invUB = WswB * dVB, invVB = WswB * dUB;
        v2f hUA = mtwo2 * invUA + one2, hVA = mtwo2 * invVA + one2;
        v2f hUB = mtwo2 * invUB + one2, hVB = mtwo2 * invVB + one2;

        sA = pack4(hUA.x, hVA.x, hUA.y, hVA.y);
        sB = pack4(hUB.x, hVB.x, hUB.y, hVB.y);

        // fc heads: one MFMA per chain, consumed 1-2 iterations later;
        // two steps' outputs merge into one float2 LDS write.
        if ((t & 1) == 0) {
            if (t >= 2 && lane < 16) {
                float2 gA = {feA[0] + feA[1], foA[0] + foA[1]};
                float2 gB = {feB[0] + feB[1], foB[0] + foB[1]};
                *(float2*)(myoutA + (t - 2)) = gA;
                *(float2*)(myoutB + (t - 2)) = gB;
            }
            feA = __builtin_amdgcn_mfma_f32_16x16x16f16(afc, sA, zfc, 0, 0, 0);
            feB = __builtin_amdgcn_mfma_f32_16x16x16f16(afc, sB, zfc, 0, 0, 0);
        } else {
            foA = __builtin_amdgcn_mfma_f32_16x16x16f16(afc, sA, zfc, 0, 0, 0);
            foB = __builtin_amdgcn_mfma_f32_16x16x16f16(afc, sB, zfc, 0, 0, 0);
        }
    }
    if (lane < 16) {
        float2 gA = {feA[0] + feA[1], foA[0] + foA[1]};
        float2 gB = {feB[0] + feB[1], foB[0] + foB[1]};
        *(float2*)(myoutA + (T_STEPS - 2)) = gA;
        *(float2*)(myoutB + (T_STEPS - 2)) = gB;
    }

    __syncthreads();

    // ---- coalesced writeout: block region out[block*64..+64)[0..30) contiguous
    float* oblk = out + (size_t)blockIdx.x * (64 * T_STEPS);
    for (int idx = tid; idx < 64 * T_STEPS; idx += BLOCK)
        oblk[idx] = tmp[idx];
}

extern "C" void kernel_launch(void* const* d_in, const int* in_sizes, int n_in,
                              void* d_out, int out_size, void* d_ws, size_t ws_size,
                              hipStream_t stream) {
    // inputs: x, T, W_ih, W_hh, b_ih, b_hh, W_fc, b_fc
    const float* x    = (const float*)d_in[0];
    const float* W_ih = (const float*)d_in[2];
    const float* W_hh = (const float*)d_in[3];
    const float* b_ih = (const float*)d_in[4];
    const float* b_hh = (const float*)d_in[5];
    const float* W_fc = (const float*)d_in[6];
    const float* b_fc = (const float*)d_in[7];
    float* out = (float*)d_out;

    const int B = in_sizes[0] / 32;      // 262144
    const int grid = B / 64;             // 4096 blocks, 64 rows each

    rnn_mfma<<<grid, BLOCK, 0, stream>>>(x, W_ih, W_hh, b_ih, b_hh, W_fc, b_fc, out);
}

// Round 6
// 115.449 us; speedup vs baseline: 1.0082x; 1.0082x over previous
//
#include <hip/hip_runtime.h>

// Elman RNN, B=262144, IN=32, H=16, T=30, OUT=1, fp32 in/out.
// Round 11: r10 (ILP-2) with the VGPR straitjacket removed.
// Post-mortem r10: ILP-2 under __launch_bounds__(128,8) was neutral — but
// that bound caps VGPR at 64 while the dual-chain state needs ~75-85, so
// the compiler SPILLED in the inner loop; scratch traffic plausibly ate
// the latency win (confounded experiment). This round is the clean A/B:
// identical kernel, __launch_bounds__(128,4) -> 128-VGPR cap, no spills,
// 4 waves/SIMD x 2 chains = 8 chains in flight (same as r9's 8 waves,
// but each wave dual-issues across independent chains).
//  - each wave owns 32 batch rows = two independent 16-row chains A/B.
//  - W fragments (whh, afc, wh*/wl*, bias) shared across chains.
//  - per-chain numerics BIT-IDENTICAL to r9/r10 (absmax 0.015625).
// Loop body per chain (r8, verified): 1 fp16 MFMA recurrence + packed-dual
// fp32 tanh (4 exp2 + ONE shared rcp product-trick) + cvt_pkrtz repack +
// pipelined fc MFMA.
// Layout invariant (verified rounds 2-4): for 16x16x16 MFMA the B-fragment
// layout == C/D layout, so tanh(acc) repacks elementwise into the next B
// operand — the state stays transposed (S = H^T), never crosses lanes.
// Decision rule: if this is ALSO neutral, both structural levers are
// exhausted with all pipes <60% => declare floor next round.

#define T_STEPS 30
#define BLOCK   128
#define SCALE   2.8853900817779268f   // 2*log2(e)

typedef _Float16 v4h __attribute__((ext_vector_type(4)));
typedef __fp16   v2fp __attribute__((ext_vector_type(2)));
typedef float    v4f __attribute__((ext_vector_type(4)));
typedef float    v2f __attribute__((ext_vector_type(2)));

struct h4 { v2fp lo, hi; };

static __device__ __forceinline__ v4h pack4(float a, float b, float c, float d) {
    h4 p;
    p.lo = __builtin_amdgcn_cvt_pkrtz(a, b);
    p.hi = __builtin_amdgcn_cvt_pkrtz(c, d);
    return __builtin_bit_cast(v4h, p);
}

__global__ __launch_bounds__(BLOCK, 4) void rnn_mfma(
    const float* __restrict__ x,     // [B, 32]
    const float* __restrict__ W_ih,  // [16, 32]
    const float* __restrict__ W_hh,  // [16, 16]
    const float* __restrict__ b_ih,  // [16]
    const float* __restrict__ b_hh,  // [16]
    const float* __restrict__ W_fc,  // [1, 16]
    const float* __restrict__ b_fc,  // [1]
    float* __restrict__ out)         // [B, 30]
{
    __shared__ float tmp[64 * T_STEPS];   // 64 rows/block x 30 steps

    const int tid  = threadIdx.x;
    const int w    = tid >> 6;        // wave in block (0..1), 32 rows each
    const int lane = tid & 63;
    const int r    = lane & 15;       // MFMA row index (batch row / A-row)
    const int q    = lane >> 4;       // quad
    const int j0   = 4 * q;

    const size_t rowA = (size_t)blockIdx.x * 64 + (size_t)w * 32 + r;
    const size_t rowB = rowA + 16;

    // ---- shared weight fragments --------------------------------------
    // A-frag (m=lane&15, k=4q+e): lane holds SCALE*W_ih[r][kh*16 + 4q+e].
    v4h wh0, wh1, wl0, wl1;
    v4f cbias;
    {
        float4 w0 = *(const float4*)(W_ih + r * 32 + 4 * q);
        float4 w1 = *(const float4*)(W_ih + r * 32 + 16 + 4 * q);
        w0.x *= SCALE; w0.y *= SCALE; w0.z *= SCALE; w0.w *= SCALE;
        w1.x *= SCALE; w1.y *= SCALE; w1.z *= SCALE; w1.w *= SCALE;
        wh0 = pack4(w0.x, w0.y, w0.z, w0.w);
        wh1 = pack4(w1.x, w1.y, w1.z, w1.w);
        wl0 = pack4(w0.x - (float)wh0[0], w0.y - (float)wh0[1],
                    w0.z - (float)wh0[2], w0.w - (float)wh0[3]);
        wl1 = pack4(w1.x - (float)wh1[0], w1.y - (float)wh1[1],
                    w1.z - (float)wh1[2], w1.w - (float)wh1[3]);
        const float4 bi = *(const float4*)(b_ih + j0);
        const float4 bh = *(const float4*)(b_hh + j0);
        cbias = (v4f){SCALE * (bi.x + bh.x), SCALE * (bi.y + bh.y),
                      SCALE * (bi.z + bh.z), SCALE * (bi.w + bh.w)};
    }

    // ---- xproj via split-precision MFMA chain, per chain ---------------
    // B-frag (k=4q+e, n=lane&15): lane holds x[row][kh*16 + 4q+e].
    v4f xpvA, xpvB;
#pragma unroll
    for (int cc = 0; cc < 2; ++cc) {
        const size_t row = cc ? rowB : rowA;
        const float4 x0 = *(const float4*)(x + row * 32 + 4 * q);
        const float4 x1 = *(const float4*)(x + row * 32 + 16 + 4 * q);
        v4h xh0 = pack4(x0.x, x0.y, x0.z, x0.w);
        v4h xh1 = pack4(x1.x, x1.y, x1.z, x1.w);
        v4h xl0 = pack4(x0.x - (float)xh0[0], x0.y - (float)xh0[1],
                        x0.z - (float)xh0[2], x0.w - (float)xh0[3]);
        v4h xl1 = pack4(x1.x - (float)xh1[0], x1.y - (float)xh1[1],
                        x1.z - (float)xh1[2], x1.w - (float)xh1[3]);
        v4f xp;
        xp = __builtin_amdgcn_mfma_f32_16x16x16f16(wh0, xh0, cbias, 0, 0, 0);
        xp = __builtin_amdgcn_mfma_f32_16x16x16f16(wh1, xh1, xp,    0, 0, 0);
        xp = __builtin_amdgcn_mfma_f32_16x16x16f16(wh0, xl0, xp,    0, 0, 0);
        xp = __builtin_amdgcn_mfma_f32_16x16x16f16(wh1, xl1, xp,    0, 0, 0);
        xp = __builtin_amdgcn_mfma_f32_16x16x16f16(wl0, xh0, xp,    0, 0, 0);
        xp = __builtin_amdgcn_mfma_f32_16x16x16f16(wl1, xh1, xp,    0, 0, 0);
        if (cc) xpvB = xp; else xpvA = xp;
    }

    // ---- W_hh A-fragment in fp16 (RNE): A[m=r][k=4q+i] = SCALE*W_hh[r][4q+i]
    v4h whh;
    {
        float4 wr = *(const float4*)(W_hh + r * 16 + 4 * q);
        whh[0] = (_Float16)(wr.x * SCALE);
        whh[1] = (_Float16)(wr.y * SCALE);
        whh[2] = (_Float16)(wr.z * SCALE);
        whh[3] = (_Float16)(wr.w * SCALE);
    }

    // ---- fc A-fragment (UNSCALED): row0 = fp16(W_fc), row1 = fp16 residual
    v4h afc;
#pragma unroll
    for (int i = 0; i < 4; ++i) {
        float wv = W_fc[4 * q + i];
        _Float16 hi = (_Float16)wv;
        _Float16 lo = (_Float16)(wv - (float)hi);
        afc[i] = (r == 0) ? hi : ((r == 1) ? lo : (_Float16)0.0f);
    }
    const float bfc = b_fc[0];
    const v4f zfc = {(q == 0) ? bfc : 0.0f, 0.0f, 0.0f, 0.0f};

    // ---- state S = H^T in fp16 (B-frag == C/D-frag layout)
    v4h sA = {(_Float16)0.0f, (_Float16)0.0f, (_Float16)0.0f, (_Float16)0.0f};
    v4h sB = sA;

    float* myoutA = &tmp[(w * 32 + r) * T_STEPS];        // lanes 0..15 write
    float* myoutB = &tmp[(w * 32 + 16 + r) * T_STEPS];

    const v2f one2  = {1.0f, 1.0f};
    const v2f mtwo2 = {-2.0f, -2.0f};

    v4f feA, foA, feB, foB;   // pipelined fc results (even / odd step)

#pragma unroll
    for (int t = 0; t < T_STEPS; ++t) {
        // Two independent chains; compiler interleaves so B fills A's stalls.
        v4f accA = __builtin_amdgcn_mfma_f32_16x16x16f16(whh, sA, xpvA, 0, 0, 0);
        v4f accB = __builtin_amdgcn_mfma_f32_16x16x16f16(whh, sB, xpvB, 0, 0, 0);

        // tanh = 1 - 2/(1+e), e = exp2(preact_scaled); packed dual-fp32
        // algebra (pairing U={0,2}, V={1,3}), ONE shared rcp per chain.
        v2f eUA = {__builtin_amdgcn_exp2f(accA[0]), __builtin_amdgcn_exp2f(accA[2])};
        v2f eVA = {__builtin_amdgcn_exp2f(accA[1]), __builtin_amdgcn_exp2f(accA[3])};
        v2f eUB = {__builtin_amdgcn_exp2f(accB[0]), __builtin_amdgcn_exp2f(accB[2])};
        v2f eVB = {__builtin_amdgcn_exp2f(accB[1]), __builtin_amdgcn_exp2f(accB[3])};

        v2f dUA = eUA + one2, dVA = eVA + one2;
        v2f dUB = eUB + one2, dVB = eVB + one2;
        v2f MA = dUA * dVA;                 // {m01, m23}
        v2f MB = dUB * dVB;
        float rrA = __builtin_amdgcn_rcpf(MA.x * MA.y);
        float rrB = __builtin_amdgcn_rcpf(MB.x * MB.y);
        v2f WswA = {rrA * MA.y, rrA * MA.x};
        v2f WswB = {rrB * MB.y, rrB * MB.x};
        v2f invUA = WswA * dVA, invVA = WswA * dUA;
        v2f invUB = WswB * dVB, invVB = WswB * dUB;
        v2f hUA = mtwo2 * invUA + one2, hVA = mtwo2 * invVA + one2;
        v2f hUB = mtwo2 * invUB + one2, hVB = mtwo2 * invVB + one2;

        sA = pack4(hUA.x, hVA.x, hUA.y, hVA.y);
        sB = pack4(hUB.x, hVB.x, hUB.y, hVB.y);

        // fc heads: one MFMA per chain, consumed 1-2 iterations later;
        // two steps' outputs merge into one float2 LDS write.
        if ((t & 1) == 0) {
            if (t >= 2 && lane < 16) {
                float2 gA = {feA[0] + feA[1], foA[0] + foA[1]};
                float2 gB = {feB[0] + feB[1], foB[0] + foB[1]};
                *(float2*)(myoutA + (t - 2)) = gA;
                *(float2*)(myoutB + (t - 2)) = gB;
            }
            feA = __builtin_amdgcn_mfma_f32_16x16x16f16(afc, sA, zfc, 0, 0, 0);
            feB = __builtin_amdgcn_mfma_f32_16x16x16f16(afc, sB, zfc, 0, 0, 0);
        } else {
            foA = __builtin_amdgcn_mfma_f32_16x16x16f16(afc, sA, zfc, 0, 0, 0);
            foB = __builtin_amdgcn_mfma_f32_16x16x16f16(afc, sB, zfc, 0, 0, 0);
        }
    }
    if (lane < 16) {
        float2 gA = {feA[0] + feA[1], foA[0] + foA[1]};
        float2 gB = {feB[0] + feB[1], foB[0] + foB[1]};
        *(float2*)(myoutA + (T_STEPS - 2)) = gA;
        *(float2*)(myoutB + (T_STEPS - 2)) = gB;
    }

    __syncthreads();

    // ---- coalesced writeout: block region out[block*64..+64)[0..30) contiguous
    float* oblk = out + (size_t)blockIdx.x * (64 * T_STEPS);
    for (int idx = tid; idx < 64 * T_STEPS; idx += BLOCK)
        oblk[idx] = tmp[idx];
}

extern "C" void kernel_launch(void* const* d_in, const int* in_sizes, int n_in,
                              void* d_out, int out_size, void* d_ws, size_t ws_size,
                              hipStream_t stream) {
    // inputs: x, T, W_ih, W_hh, b_ih, b_hh, W_fc, b_fc
    const float* x    = (const float*)d_in[0];
    const float* W_ih = (const float*)d_in[2];
    const float* W_hh = (const float*)d_in[3];
    const float* b_ih = (const float*)d_in[4];
    const float* b_hh = (const float*)d_in[5];
    const float* W_fc = (const float*)d_in[6];
    const float* b_fc = (const float*)d_in[7];
    float* out = (float*)d_out;

    const int B = in_sizes[0] / 32;      // 262144
    const int grid = B / 64;             // 4096 blocks, 64 rows each

    rnn_mfma<<<grid, BLOCK, 0, stream>>>(x, W_ih, W_hh, b_ih, b_hh, W_fc, b_fc, out);
}